// Round 4
// baseline (250.198 us; speedup 1.0000x reference)
//
#include <hip/hip_runtime.h>

#define TPB 256
#define U 8                  // independent 16B NT loads per array per thread per iter
#define CHUNK (TPB * U)      // float4s per chunk (2048)
#define NBLK 2048            // 8 blocks/CU; partials = 16 KB of d_ws

typedef float vf4 __attribute__((ext_vector_type(4)));

__device__ __forceinline__ float relf(float x, float y) {
    float d = fabsf(x - y);
    float r = d * __builtin_amdgcn_rcpf(y);   // ~1 ulp; matches reference within tol
    return (y == 0.0f) ? d : r;               // branchless cndmask
}

__global__ __launch_bounds__(TPB) void rdl_partial_kernel(
    const vf4* __restrict__ x, const vf4* __restrict__ y,
    double* __restrict__ partial, int nvec) {

    const int t = threadIdx.x;
    double accd = 0.0;

    // Pure-HBM NT streaming (round-3 result: NT-both >> cached, harness
    // re-poison churns L3 every iter). This round: force deep per-wave MLP
    // -- 16 independent dwordx4 NT loads in flight per thread (round-1
    // VGPR_Count=24 proved the compiler serialized the U=4 burst to ~3
    // outstanding; 16 in flight needs ~64 data VGPRs, occupancy still
    // 5-6 waves/SIMD).
    const int nchunk = nvec / CHUNK;
    for (int c = blockIdx.x; c < nchunk; c += gridDim.x) {
        const int base = c * CHUNK + t;
        vf4 xv[U], yv[U];
        #pragma unroll
        for (int u = 0; u < U; ++u)
            xv[u] = __builtin_nontemporal_load(x + base + u * TPB);
        #pragma unroll
        for (int u = 0; u < U; ++u)
            yv[u] = __builtin_nontemporal_load(y + base + u * TPB);

        float a0 = 0.f, a1 = 0.f;   // short f32 chains (64 terms), promoted below
        #pragma unroll
        for (int u = 0; u < U; ++u) {
            a0 += relf(xv[u][0], yv[u][0]) + relf(xv[u][2], yv[u][2]);
            a1 += relf(xv[u][1], yv[u][1]) + relf(xv[u][3], yv[u][3]);
        }
        accd += (double)(a0 + a1);
    }

    // tail (empty for N=2^25: CHUNK divides nvec), kept for generality
    for (int i = nchunk * CHUNK + blockIdx.x * TPB + t; i < nvec;
         i += gridDim.x * TPB) {
        vf4 xv = x[i], yv = y[i];
        accd += (double)(relf(xv[0], yv[0]) + relf(xv[2], yv[2])
                       + relf(xv[1], yv[1]) + relf(xv[3], yv[3]));
    }

    // wave (64-lane) f64 reduction
    double acc = accd;
    for (int off = 32; off > 0; off >>= 1)
        acc += __shfl_down(acc, off, 64);
    __shared__ double smem[TPB / 64];
    const int lane = t & 63, w = t >> 6;
    if (lane == 0) smem[w] = acc;
    __syncthreads();
    if (t == 0) {
        double s = 0.0;
        #pragma unroll
        for (int wi = 0; wi < TPB / 64; ++wi) s += smem[wi];
        partial[blockIdx.x] = s;
    }
}

__global__ __launch_bounds__(TPB) void rdl_final_kernel(
    const double* __restrict__ partial, float* __restrict__ out,
    int nblocks, double invN) {
    double acc = 0.0;
    for (int i = threadIdx.x; i < nblocks; i += TPB)
        acc += partial[i];
    for (int off = 32; off > 0; off >>= 1)
        acc += __shfl_down(acc, off, 64);
    __shared__ double smem[TPB / 64];
    const int lane = threadIdx.x & 63, wid = threadIdx.x >> 6;
    if (lane == 0) smem[wid] = acc;
    __syncthreads();
    if (threadIdx.x == 0) {
        double s = 0.0;
        #pragma unroll
        for (int w = 0; w < TPB / 64; ++w) s += smem[w];
        out[0] = (float)(s * invN);
    }
}

extern "C" void kernel_launch(void* const* d_in, const int* in_sizes, int n_in,
                              void* d_out, int out_size, void* d_ws, size_t ws_size,
                              hipStream_t stream) {
    const float* x = (const float*)d_in[0];
    const float* y = (const float*)d_in[1];
    int n = in_sizes[0];          // 33554432, divisible by 4
    int nvec = n / 4;

    double* partial = (double*)d_ws;   // NBLK * 8 = 16 KB scratch

    rdl_partial_kernel<<<NBLK, TPB, 0, stream>>>(
        (const vf4*)x, (const vf4*)y, partial, nvec);
    rdl_final_kernel<<<1, TPB, 0, stream>>>(
        partial, (float*)d_out, NBLK, 1.0 / (double)n);
}